// Round 9
// baseline (312.388 us; speedup 1.0000x reference)
//
#include <hip/hip_runtime.h>
#include <math.h>

#define IN_DIM 128
#define NH 8
#define OC 16
#define HC 128   // NH*OC
#define BSTR 136   // padded bf16 LDS stride (16B-aligned rows)
#define DPB 256    // dst nodes per coarse bin (bin = dst >> 8)
#define NBMAX 256
#define ECH 4096   // edges per chunk in binning kernels

typedef __attribute__((ext_vector_type(8))) short short8;
typedef __attribute__((ext_vector_type(4))) float f32x4;

__device__ __forceinline__ unsigned short bf16_rne(float f) {
  unsigned int u = __builtin_bit_cast(unsigned int, f);
  u += 0x7FFFu + ((u >> 16) & 1u);
  return (unsigned short)(u >> 16);
}
__device__ __forceinline__ float bf16_to_f(unsigned short h) {
  unsigned int u = ((unsigned int)h) << 16;
  return __builtin_bit_cast(float, u);
}

// ---------------- K0: feature -> bf16 hi/lo split, streaming -------------
// Removes all per-strip fp32->bf16 VALU from the GEMM kernels.
__global__ __launch_bounds__(256) void k0_cvt(const float* __restrict__ feature,
                                              unsigned short* __restrict__ fhi,
                                              unsigned short* __restrict__ flo,
                                              int total4) {  // total/4
  for (int i = blockIdx.x * 256 + threadIdx.x; i < total4; i += gridDim.x * 256) {
    const float4 f = ((const float4*)feature)[i];
    ushort4 h, l;
    h.x = bf16_rne(f.x); l.x = bf16_rne(f.x - bf16_to_f(h.x));
    h.y = bf16_rne(f.y); l.y = bf16_rne(f.y - bf16_to_f(h.y));
    h.z = bf16_rne(f.z); l.z = bf16_rne(f.z - bf16_to_f(h.z));
    h.w = bf16_rne(f.w); l.w = bf16_rne(f.w - bf16_to_f(h.w));
    ((ushort4*)fhi)[i] = h;
    ((ushort4*)flo)[i] = l;
  }
}

// ---------------- K1a: xbf = bf16(fhi @ w_lin-hi) ------------------------
// Single-MFMA (A-hi x B-hi): xbf feeds int8 quant + logits; round-5
// empirically validated (absmax identical). 34.8 KB LDS -> 4 blocks/CU.
__global__ __launch_bounds__(256, 4) void k1a_x(const unsigned short* __restrict__ fhi,
                                                const float* __restrict__ w_lin,
                                                unsigned short* __restrict__ xbf,
                                                int N) {
  __shared__ unsigned short BL[HC * BSTR];
  const int t = threadIdx.x;
  for (int i = t; i < IN_DIM * HC; i += 256) {
    const int r = i >> 7, c = i & 127;  // W[k=r][col=c]
    BL[c * BSTR + r] = bf16_rne(w_lin[i]);
  }
  __syncthreads();

  const int wave = t >> 6, lane = t & 63;
  const int n16 = lane & 15, quad = lane >> 4;
  const int nStrips = (N + 15) >> 4;

  for (int strip = blockIdx.x * 4 + wave; strip < nStrips; strip += gridDim.x * 4) {
    const int row0 = strip * 16;
    const int arow = row0 + n16;
    const unsigned short* __restrict__ ap =
        fhi + (size_t)((arow < N) ? arow : 0) * IN_DIM + quad * 8;
    short8 ah[4];
#pragma unroll
    for (int ks = 0; ks < 4; ++ks) ah[ks] = *(const short8*)(ap + ks * 32);

#pragma unroll
    for (int cg = 0; cg < 2; ++cg) {
      f32x4 acc[4] = {{0.f,0.f,0.f,0.f},{0.f,0.f,0.f,0.f},{0.f,0.f,0.f,0.f},{0.f,0.f,0.f,0.f}};
#pragma unroll
      for (int ks = 0; ks < 4; ++ks) {
#pragma unroll
        for (int j = 0; j < 4; ++j) {
          const int boff = ((cg * 4 + j) * 16 + n16) * BSTR + ks * 32 + quad * 8;
          const short8 bh = *(const short8*)&BL[boff];
          acc[j] = __builtin_amdgcn_mfma_f32_16x16x32_bf16(ah[ks], bh, acc[j], 0, 0, 0);
        }
      }
#pragma unroll
      for (int j = 0; j < 4; ++j) {
        const int colo = (cg * 4 + j) * 16 + n16;
#pragma unroll
        for (int r = 0; r < 4; ++r) {
          const int rr = row0 + quad * 4 + r;
          if (rr < N) xbf[(size_t)rr * HC + colo] = bf16_rne(acc[j][r]);
        }
      }
    }
  }
}

// ---------------- K1c: out = (fhi+flo) @ w_res-hi (residual) -------------
// Split-A (2 MFMA) keeps the directly-compared residual accurate.
__global__ __launch_bounds__(256, 4) void k1c_res(const unsigned short* __restrict__ fhi,
                                                  const unsigned short* __restrict__ flo,
                                                  const float* __restrict__ w_res,
                                                  float* __restrict__ out, int N) {
  __shared__ unsigned short BR[HC * BSTR];
  const int t = threadIdx.x;
  for (int i = t; i < IN_DIM * HC; i += 256) {
    const int r = i >> 7, c = i & 127;
    BR[c * BSTR + r] = bf16_rne(w_res[i]);
  }
  __syncthreads();

  const int wave = t >> 6, lane = t & 63;
  const int n16 = lane & 15, quad = lane >> 4;
  const int nStrips = (N + 15) >> 4;

  for (int strip = blockIdx.x * 4 + wave; strip < nStrips; strip += gridDim.x * 4) {
    const int row0 = strip * 16;
    const int arow = row0 + n16;
    const size_t abase = (size_t)((arow < N) ? arow : 0) * IN_DIM + quad * 8;
    short8 ahi[4], alo[4];
#pragma unroll
    for (int ks = 0; ks < 4; ++ks) {
      ahi[ks] = *(const short8*)(fhi + abase + ks * 32);
      alo[ks] = *(const short8*)(flo + abase + ks * 32);
    }
#pragma unroll
    for (int cg = 0; cg < 2; ++cg) {
      f32x4 acc[4] = {{0.f,0.f,0.f,0.f},{0.f,0.f,0.f,0.f},{0.f,0.f,0.f,0.f},{0.f,0.f,0.f,0.f}};
#pragma unroll
      for (int ks = 0; ks < 4; ++ks) {
#pragma unroll
        for (int j = 0; j < 4; ++j) {
          const int boff = ((cg * 4 + j) * 16 + n16) * BSTR + ks * 32 + quad * 8;
          const short8 bh = *(const short8*)&BR[boff];
          acc[j] = __builtin_amdgcn_mfma_f32_16x16x32_bf16(ahi[ks], bh, acc[j], 0, 0, 0);
          acc[j] = __builtin_amdgcn_mfma_f32_16x16x32_bf16(alo[ks], bh, acc[j], 0, 0, 0);
        }
      }
#pragma unroll
      for (int j = 0; j < 4; ++j) {
        const int colo = (cg * 4 + j) * 16 + n16;
#pragma unroll
        for (int r = 0; r < 4; ++r) {
          const int rr = row0 + quad * 4 + r;
          if (rr < N) out[(size_t)rr * HC + colo] = acc[j][r];
        }
      }
    }
  }
}

// ---------------- K1b: al/ar logits + row-scaled int8 quant of x ---------
__global__ __launch_bounds__(256) void k1b_attn(const unsigned short* __restrict__ xbf,
                                                const float* __restrict__ att_l,
                                                const float* __restrict__ att_r,
                                                float* __restrict__ al,
                                                float* __restrict__ ar,
                                                char* __restrict__ x8,
                                                float* __restrict__ s, int N) {
  const int idx = blockIdx.x * 256 + threadIdx.x;
  if (idx >= N * NH) return;
  const int h = idx & (NH - 1);
  const int n = idx >> 3;
  const ushort4* xp = (const ushort4*)(xbf + (size_t)idx * OC);
  const float4* lp = (const float4*)(att_l + h * OC);
  const float4* rp = (const float4*)(att_r + h * OC);
  float f[16];
  float sl = 0.f, sr = 0.f, m = 0.f;
#pragma unroll
  for (int q = 0; q < 4; ++q) {
    const ushort4 xu = xp[q];
    const float4 lv = lp[q], rv = rp[q];
    f[q * 4 + 0] = bf16_to_f(xu.x);
    f[q * 4 + 1] = bf16_to_f(xu.y);
    f[q * 4 + 2] = bf16_to_f(xu.z);
    f[q * 4 + 3] = bf16_to_f(xu.w);
    sl += f[q*4+0] * lv.x + f[q*4+1] * lv.y + f[q*4+2] * lv.z + f[q*4+3] * lv.w;
    sr += f[q*4+0] * rv.x + f[q*4+1] * rv.y + f[q*4+2] * rv.z + f[q*4+3] * rv.w;
#pragma unroll
    for (int j = 0; j < 4; ++j) m = fmaxf(m, fabsf(f[q * 4 + j]));
  }
  al[idx] = sl;
  ar[idx] = sr;
  m = fmaxf(m, __shfl_xor(m, 1, 64));
  m = fmaxf(m, __shfl_xor(m, 2, 64));
  m = fmaxf(m, __shfl_xor(m, 4, 64));
  const float inv = (m > 0.f) ? 127.f / m : 0.f;
  int4 pk;
  int* pw = (int*)&pk;
#pragma unroll
  for (int w = 0; w < 4; ++w) {
    int b0 = (int)rintf(f[w * 4 + 0] * inv);
    int b1 = (int)rintf(f[w * 4 + 1] * inv);
    int b2 = (int)rintf(f[w * 4 + 2] * inv);
    int b3 = (int)rintf(f[w * 4 + 3] * inv);
    pw[w] = (b0 & 0xFF) | ((b1 & 0xFF) << 8) | ((b2 & 0xFF) << 16) | ((b3 & 0xFF) << 24);
  }
  *(int4*)(x8 + (size_t)n * HC + h * 16) = pk;
  if (h == 0) s[n] = (m > 0.f) ? m / 127.f : 0.f;
}

// ---------------- K4a: coarse-bin histogram (bin = dst>>8) ---------------
__global__ __launch_bounds__(256) void k4a_count(const int* __restrict__ edst,
                                                 int* __restrict__ bin_count, int E) {
  __shared__ int cnt[NBMAX];
  const int t = threadIdx.x;
  cnt[t] = 0;
  __syncthreads();
  const int base = blockIdx.x * ECH;
#pragma unroll
  for (int j = 0; j < ECH / 256; ++j) {
    const int e = base + j * 256 + t;
    if (e < E) atomicAdd(&cnt[edst[e] >> 8], 1);
  }
  __syncthreads();
  if (cnt[t] > 0) atomicAdd(&bin_count[t], cnt[t]);
}

// ---------------- K3: scan bin counts -> bin_ofs / bin_cursor ------------
__global__ __launch_bounds__(NBMAX) void k3_bins(const int* __restrict__ bin_count,
                                                 int* __restrict__ bin_ofs,
                                                 int* __restrict__ bin_cursor,
                                                 int* __restrict__ row_start, int N) {
  __shared__ int s[NBMAX];
  const int t = threadIdx.x;
  const int own = bin_count[t];
  s[t] = own;
  __syncthreads();
  for (int o = 1; o < NBMAX; o <<= 1) {
    const int a = (t >= o) ? s[t - o] : 0;
    __syncthreads();
    s[t] += a;
    __syncthreads();
  }
  const int ex = s[t] - own;
  bin_ofs[t] = ex;
  bin_cursor[t] = ex;
  if (t == NBMAX - 1) {
    bin_ofs[NBMAX] = s[t];
    row_start[N] = s[t];  // = E
  }
}

// ---------------- K4b: bin-scatter with LDS write-combining --------------
__global__ __launch_bounds__(256) void k4b_bin(const int* __restrict__ esrc,
                                               const int* __restrict__ edst,
                                               const float* __restrict__ ew,
                                               int* __restrict__ bin_cursor,
                                               uint2* __restrict__ tmp, int E) {
  __shared__ int cnt[NBMAX];
  __shared__ int s[NBMAX];
  __shared__ int ofs[NBMAX];
  __shared__ int gbase[NBMAX];
  __shared__ uint2 data[ECH];  // 32 KB
  const int t = threadIdx.x;
  cnt[t] = 0;
  __syncthreads();
  const int base = blockIdx.x * ECH;
  uint2 v[16];
  int bj[16], sj[16];
#pragma unroll
  for (int j = 0; j < 16; ++j) {
    const int e = base + j * 256 + t;
    bj[j] = -1;
    if (e < E) {
      const int d = edst[e];
      v[j] = make_uint2((unsigned)esrc[e] | ((unsigned)(d & (DPB - 1)) << 16),
                        __float_as_uint(ew[e]));
      bj[j] = d >> 8;
      sj[j] = atomicAdd(&cnt[bj[j]], 1);
    }
  }
  __syncthreads();
  const int own = cnt[t];
  s[t] = own;
  __syncthreads();
  for (int o = 1; o < NBMAX; o <<= 1) {
    const int a = (t >= o) ? s[t - o] : 0;
    __syncthreads();
    s[t] += a;
    __syncthreads();
  }
  ofs[t] = s[t] - own;
  if (own > 0) gbase[t] = atomicAdd(&bin_cursor[t], own);
  __syncthreads();
#pragma unroll
  for (int j = 0; j < 16; ++j)
    if (bj[j] >= 0) data[ofs[bj[j]] + sj[j]] = v[j];
  __syncthreads();
  const int cc = (base + ECH <= E) ? ECH : (E - base);
  for (int i = t; i < cc; i += 256) {
    int lo = 0, hi = NBMAX - 1;
    while (hi - lo > 1) {
      const int mid = (lo + hi) >> 1;
      if (ofs[mid] <= i) lo = mid; else hi = mid;
    }
    tmp[gbase[lo] + (i - ofs[lo])] = data[i];
  }
}

// ---------------- K4c: per-bin dst-sort -> final CSR + row_start ---------
__global__ __launch_bounds__(256) void k4c_sort(const uint2* __restrict__ tmp,
                                                const int* __restrict__ bin_ofs,
                                                uint2* __restrict__ packed,
                                                int* __restrict__ row_start, int N) {
  const int b = blockIdx.x, t = threadIdx.x;
  const int gstart = bin_ofs[b];
  const int M = bin_ofs[b + 1] - gstart;
  __shared__ int cnt[DPB];
  __shared__ int s[DPB];
  __shared__ int cur[DPB];
  __shared__ int ccnt[DPB];
  __shared__ int cofs[DPB + 1];
  __shared__ uint2 data[ECH];  // 32 KB
  cnt[t] = 0;
  __syncthreads();
  for (int i = t; i < M; i += 256) atomicAdd(&cnt[tmp[gstart + i].x >> 16], 1);
  __syncthreads();
  {
    const int own = cnt[t];
    s[t] = own;
    __syncthreads();
    for (int o = 1; o < DPB; o <<= 1) {
      const int a = (t >= o) ? s[t - o] : 0;
      __syncthreads();
      s[t] += a;
      __syncthreads();
    }
    const int ex = s[t] - own;
    cur[t] = gstart + ex;
    const int node = b * DPB + t;
    if (node < N) row_start[node] = gstart + ex;
  }
  __syncthreads();
  for (int cb = 0; cb < M; cb += ECH) {
    const int cc = min(ECH, M - cb);
    ccnt[t] = 0;
    __syncthreads();
    uint2 v[16];
    int dj[16], sj[16];
#pragma unroll
    for (int j = 0; j < 16; ++j) {
      const int li = j * 256 + t;
      dj[j] = -1;
      if (li < cc) {
        v[j] = tmp[gstart + cb + li];
        dj[j] = (int)(v[j].x >> 16);
        sj[j] = atomicAdd(&ccnt[dj[j]], 1);
      }
    }
    __syncthreads();
    const int cown = ccnt[t];
    s[t] = cown;
    __syncthreads();
    for (int o = 1; o < DPB; o <<= 1) {
      const int a = (t >= o) ? s[t - o] : 0;
      __syncthreads();
      s[t] += a;
      __syncthreads();
    }
    cofs[t] = s[t] - cown;
    if (t == 0) cofs[DPB] = cc;
    __syncthreads();
#pragma unroll
    for (int j = 0; j < 16; ++j)
      if (dj[j] >= 0) data[cofs[dj[j]] + sj[j]] = make_uint2(v[j].x & 0xFFFFu, v[j].y);
    __syncthreads();
    for (int i = t; i < cc; i += 256) {
      int lo = 0, hi = DPB;
      while (hi - lo > 1) {
        const int mid = (lo + hi) >> 1;
        if (cofs[mid] <= i) lo = mid; else hi = mid;
      }
      packed[cur[lo] + (i - cofs[lo])] = data[i];
    }
    __syncthreads();
    cur[t] += ccnt[t];
    __syncthreads();
  }
}

// ---------------- K5: ONE WAVE PER NODE, barrier-free fused loop ---------
__global__ __launch_bounds__(64) void k5_agg(const char* __restrict__ x8,
                                             const float* __restrict__ s,
                                             const uint2* __restrict__ packed,
                                             const int* __restrict__ row_start,
                                             const float* __restrict__ al,
                                             const float* __restrict__ ar,
                                             float* __restrict__ out, int N) {
  const int n = blockIdx.x;
  const int l = threadIdx.x;
  const int s0 = row_start[n];
  const int En = row_start[n + 1] - s0;
  if (En == 0) return;  // out already holds residual; elu(0)=0
  __shared__ int sbuf[64];
  __shared__ float wbuf[64];
  __shared__ float scbuf[64];
  const int h = l & 7;   // my head == head of my channel block
  const int g = l >> 3;  // my edge residue
  const int ch0 = h * 16;

  const float arn = ar[(size_t)n * NH + h];
  float dpart = 0.f;
  float f[16];
#pragma unroll
  for (int j = 0; j < 16; ++j) f[j] = 0.f;

  for (int base = 0; base < En; base += 64) {
    const int cnt = min(64, En - base);
    __syncthreads();
    if (l < cnt) {
      const uint2 p = packed[s0 + base + l];
      const int src = (int)p.x;
      sbuf[l] = src;
      wbuf[l] = __uint_as_float(p.y);
      scbuf[l] = s[src];
    }
    __syncthreads();
    for (int i = g; i < cnt; i += 8) {
      const int src = sbuf[i];
      float a = wbuf[i] * (al[(size_t)src * NH + h] + arn);
      a = (a > 0.f) ? a : 0.2f * a;
      const float e = __expf(a);
      dpart += e;
      const float fac = e * scbuf[i];
      const int4 qw = *(const int4*)(x8 + (size_t)src * HC + ch0);
      f[0]  = fmaf(fac, (float)(char)(qw.x),        f[0]);
      f[1]  = fmaf(fac, (float)(char)(qw.x >> 8),   f[1]);
      f[2]  = fmaf(fac, (float)(char)(qw.x >> 16),  f[2]);
      f[3]  = fmaf(fac, (float)(qw.x >> 24),        f[3]);
      f[4]  = fmaf(fac, (float)(char)(qw.y),        f[4]);
      f[5]  = fmaf(fac, (float)(char)(qw.y >> 8),   f[5]);
      f[6]  = fmaf(fac, (float)(char)(qw.y >> 16),  f[6]);
      f[7]  = fmaf(fac, (float)(qw.y >> 24),        f[7]);
      f[8]  = fmaf(fac, (float)(char)(qw.z),        f[8]);
      f[9]  = fmaf(fac, (float)(char)(qw.z >> 8),   f[9]);
      f[10] = fmaf(fac, (float)(char)(qw.z >> 16),  f[10]);
      f[11] = fmaf(fac, (float)(qw.z >> 24),        f[11]);
      f[12] = fmaf(fac, (float)(char)(qw.w),        f[12]);
      f[13] = fmaf(fac, (float)(char)(qw.w >> 8),   f[13]);
      f[14] = fmaf(fac, (float)(char)(qw.w >> 16),  f[14]);
      f[15] = fmaf(fac, (float)(qw.w >> 24),        f[15]);
    }
  }
  dpart += __shfl_xor(dpart, 8);
  dpart += __shfl_xor(dpart, 16);
  dpart += __shfl_xor(dpart, 32);
  const float inv = 1.f / dpart;
#pragma unroll
  for (int j = 0; j < 16; ++j) {
    f[j] += __shfl_xor(f[j], 8);
    f[j] += __shfl_xor(f[j], 16);
    f[j] += __shfl_xor(f[j], 32);
  }
  if (g == 0) {  // lanes 0..7 write 16 channels each
    float* __restrict__ outp = out + (size_t)n * HC + ch0;
#pragma unroll
    for (int j = 0; j < 16; ++j) {
      const float feat = f[j] * inv;
      const float o = (feat > 0.f) ? feat : (__expf(feat) - 1.f);  // elu
      outp[j] += o;  // out already holds the residual from k1c
    }
  }
}

extern "C" void kernel_launch(void* const* d_in, const int* in_sizes, int n_in,
                              void* d_out, int out_size, void* d_ws, size_t ws_size,
                              hipStream_t stream) {
  const float* feature = (const float*)d_in[0];
  const int* esrc = (const int*)d_in[1];
  const int* edst = (const int*)d_in[2];
  const float* ew = (const float*)d_in[3];
  const float* w_lin = (const float*)d_in[4];
  const float* att_l = (const float*)d_in[5];
  const float* att_r = (const float*)d_in[6];
  const float* w_res = (const float*)d_in[7];
  float* out = (float*)d_out;

  const int N = in_sizes[0] / IN_DIM;
  const int E = in_sizes[1];
  const int NB = (N + DPB - 1) / DPB;
  const int nch = (E + ECH - 1) / ECH;
  const int nStrips = (N + 15) >> 4;

  char* ws = (char*)d_ws;
  size_t off = 0;
  auto alloc = [&](size_t bytes) {
    void* p = ws + off;
    off = (off + bytes + 255) & ~(size_t)255;
    return p;
  };
  unsigned short* fhi = (unsigned short*)alloc((size_t)N * IN_DIM * sizeof(unsigned short));
  unsigned short* flo = (unsigned short*)alloc((size_t)N * IN_DIM * sizeof(unsigned short));
  unsigned short* xbf = (unsigned short*)alloc((size_t)N * HC * sizeof(unsigned short));
  char* x8 = (char*)alloc((size_t)N * HC);
  float* sscale = (float*)alloc((size_t)N * sizeof(float));
  float* al = (float*)alloc((size_t)N * NH * sizeof(float));
  float* ar = (float*)alloc((size_t)N * NH * sizeof(float));
  int* row_start = (int*)alloc((size_t)(N + 1) * sizeof(int));
  int* bin_count = (int*)alloc((size_t)NBMAX * sizeof(int));
  int* bin_ofs = (int*)alloc((size_t)(NBMAX + 1) * sizeof(int));
  int* bin_cursor = (int*)alloc((size_t)NBMAX * sizeof(int));
  uint2* tmp = (uint2*)alloc((size_t)E * sizeof(uint2));
  uint2* packed = (uint2*)alloc((size_t)E * sizeof(uint2));

  hipMemsetAsync(bin_count, 0, (size_t)NBMAX * sizeof(int), stream);
  k0_cvt<<<1024, 256, 0, stream>>>(feature, fhi, flo, N * IN_DIM / 4);
  k1a_x<<<(nStrips + 3) / 4, 256, 0, stream>>>(fhi, w_lin, xbf, N);
  k1c_res<<<(nStrips + 3) / 4, 256, 0, stream>>>(fhi, flo, w_res, out, N);
  k1b_attn<<<(N * NH + 255) / 256, 256, 0, stream>>>(xbf, att_l, att_r, al, ar, x8, sscale, N);
  k4a_count<<<nch, 256, 0, stream>>>(edst, bin_count, E);
  k3_bins<<<1, NBMAX, 0, stream>>>(bin_count, bin_ofs, bin_cursor, row_start, N);
  k4b_bin<<<nch, 256, 0, stream>>>(esrc, edst, ew, bin_cursor, tmp, E);
  k4c_sort<<<NB, 256, 0, stream>>>(tmp, bin_ofs, packed, row_start, N);
  k5_agg<<<N, 64, 0, stream>>>(x8, sscale, packed, row_start, al, ar, out, N);
}